// Round 1
// baseline (785.886 us; speedup 1.0000x reference)
//
#include <hip/hip_runtime.h>

#define NFEAT 128

// ---------------- degree histogram ----------------
__global__ void k_deg(const int* __restrict__ dst, int* __restrict__ deg, int E) {
  int e = blockIdx.x * blockDim.x + threadIdx.x;
  if (e < E) atomicAdd(&deg[dst[e]], 1);
}

// ---------------- 2-level exclusive scan ----------------
__global__ __launch_bounds__(1024) void k_scan_blocks(const int* __restrict__ deg,
    int* __restrict__ base, int* __restrict__ partials, int n) {
  __shared__ int buf[1024];
  int tid = threadIdx.x;
  int i = blockIdx.x * 1024 + tid;
  int v = (i < n) ? deg[i] : 0;
  buf[tid] = v;
  __syncthreads();
  #pragma unroll
  for (int off = 1; off < 1024; off <<= 1) {
    int t = (tid >= off) ? buf[tid - off] : 0;
    __syncthreads();
    buf[tid] += t;
    __syncthreads();
  }
  if (i < n) base[i] = buf[tid] - v;   // exclusive prefix within block
  if (tid == 1023) partials[blockIdx.x] = buf[tid];
}

__global__ void k_scan_partials(int* __restrict__ partials, int nb) {
  __shared__ int buf[128];
  int tid = threadIdx.x;
  int v = (tid < nb) ? partials[tid] : 0;
  buf[tid] = v;
  __syncthreads();
  #pragma unroll
  for (int off = 1; off < 128; off <<= 1) {
    int t = (tid >= off) ? buf[tid - off] : 0;
    __syncthreads();
    buf[tid] += t;
    __syncthreads();
  }
  if (tid < nb) partials[tid] = buf[tid] - v;  // exclusive
}

__global__ void k_finalize_base(int* __restrict__ base, const int* __restrict__ partials,
    const int* __restrict__ deg, float* __restrict__ dinv, int n, int E) {
  int i = blockIdx.x * blockDim.x + threadIdx.x;
  if (i < n) {
    base[i] += partials[i >> 10];
    dinv[i] = rsqrtf((float)(deg[i] + 1));   // +1 self-loop, deg>=1 -> no zeros
  } else if (i == n) {
    base[n] = E;
  }
}

// ---------------- bucket scatter: build CSR src lists ----------------
__global__ void k_scatter(const int* __restrict__ src, const int* __restrict__ dst,
    const int* __restrict__ base, int* __restrict__ cursor, int* __restrict__ ssrc, int E) {
  int e = blockIdx.x * blockDim.x + threadIdx.x;
  if (e < E) {
    int d = dst[e];
    int pos = base[d] + atomicAdd(&cursor[d], 1);
    ssrc[pos] = src[e];
  }
}

// ---------------- C[r][:] = (A[r][:] @ B) * dinv[r]  (A: nrows x 128, B: 128 x 128)
__global__ __launch_bounds__(512) void k_gemm_scale(const float* __restrict__ A,
    const float* __restrict__ B, const float* __restrict__ dinv,
    float* __restrict__ C, int nrows) {
  int cg = threadIdx.x & 31;   // 32 col groups of 4 cols
  int rg = threadIdx.x >> 5;   // 16 row groups of 4 rows
  int r0 = blockIdx.x * 64 + rg * 4;
  int c0 = cg * 4;
  float acc[4][4] = {};
  int rr[4];
  #pragma unroll
  for (int i = 0; i < 4; i++) { int r = r0 + i; rr[i] = (r < nrows) ? r : (nrows - 1); }

  for (int k = 0; k < 128; k += 4) {
    float4 a[4];
    #pragma unroll
    for (int i = 0; i < 4; i++)
      a[i] = *(const float4*)(A + (size_t)rr[i] * NFEAT + k);
    float4 w[4];
    #pragma unroll
    for (int kk = 0; kk < 4; kk++)
      w[kk] = *(const float4*)(B + (size_t)(k + kk) * NFEAT + c0);
    #pragma unroll
    for (int i = 0; i < 4; i++) {
      const float av[4] = {a[i].x, a[i].y, a[i].z, a[i].w};
      #pragma unroll
      for (int kk = 0; kk < 4; kk++) {
        acc[i][0] += av[kk] * w[kk].x;
        acc[i][1] += av[kk] * w[kk].y;
        acc[i][2] += av[kk] * w[kk].z;
        acc[i][3] += av[kk] * w[kk].w;
      }
    }
  }
  #pragma unroll
  for (int i = 0; i < 4; i++) {
    int r = r0 + i;
    if (r < nrows) {
      float s = dinv[r];
      float4 o = make_float4(acc[i][0] * s, acc[i][1] * s, acc[i][2] * s, acc[i][3] * s);
      *(float4*)(C + (size_t)r * NFEAT + c0) = o;
    }
  }
}

// ---------------- per-node aggregation: out = relu(dinv[n]*(sum_src g + g[n]) + b)
__global__ __launch_bounds__(128) void k_agg(const float* __restrict__ g,
    const float* __restrict__ dinv, const int* __restrict__ base,
    const int* __restrict__ ssrc, const float* __restrict__ bias,
    float* __restrict__ out, int do_relu) {
  int n = blockIdx.x;
  int f = threadIdx.x;   // 0..127
  int b0 = base[n], b1 = base[n + 1];
  float acc = g[(size_t)n * NFEAT + f];   // self term (already scaled by dinv[n])
  int e = b0;
  for (; e + 4 <= b1; e += 4) {
    int s0 = ssrc[e], s1 = ssrc[e + 1], s2 = ssrc[e + 2], s3 = ssrc[e + 3];
    float v0 = g[(size_t)s0 * NFEAT + f];
    float v1 = g[(size_t)s1 * NFEAT + f];
    float v2 = g[(size_t)s2 * NFEAT + f];
    float v3 = g[(size_t)s3 * NFEAT + f];
    acc += v0; acc += v1; acc += v2; acc += v3;
  }
  for (; e < b1; ++e) acc += g[(size_t)ssrc[e] * NFEAT + f];
  float r = acc * dinv[n] + bias[f];
  out[(size_t)n * NFEAT + f] = do_relu ? fmaxf(r, 0.f) : r;
}

// ---------------- final GEMV: out[n] = h[n][:] . Wlin + blin ----------------
__global__ __launch_bounds__(256) void k_final(const float* __restrict__ h,
    const float* __restrict__ wlin, const float* __restrict__ blin,
    float* __restrict__ out, int n) {
  int wave = threadIdx.x >> 6;
  int lane = threadIdx.x & 63;
  int node = blockIdx.x * 4 + wave;
  if (node >= n) return;
  float2 v = *(const float2*)(h + (size_t)node * NFEAT + lane * 2);
  float2 w = *(const float2*)(wlin + lane * 2);
  float acc = v.x * w.x + v.y * w.y;
  #pragma unroll
  for (int off = 32; off >= 1; off >>= 1) acc += __shfl_down(acc, off, 64);
  if (lane == 0) out[node] = acc + blin[0];
}

extern "C" void kernel_launch(void* const* d_in, const int* in_sizes, int n_in,
                              void* d_out, int out_size, void* d_ws, size_t ws_size,
                              hipStream_t stream) {
  const float* x    = (const float*)d_in[0];
  const int*   ei   = (const int*)d_in[1];
  const float* W1   = (const float*)d_in[2];
  const float* b1   = (const float*)d_in[3];
  const float* W2   = (const float*)d_in[4];
  const float* b2   = (const float*)d_in[5];
  const float* Wlin = (const float*)d_in[6];
  const float* blin = (const float*)d_in[7];
  const int N = in_sizes[0] / NFEAT;
  const int E = in_sizes[1] / 2;
  const int* src = ei;       // edge_index[0]
  const int* dst = ei + E;   // edge_index[1]

  // workspace layout (4B elements)
  int* ws_i = (int*)d_ws;
  size_t off = 0;
  int* deg     = ws_i + off; off += N;
  int* cursor  = ws_i + off; off += N;             // adjacent to deg -> one memset
  int* base    = ws_i + off; off += (size_t)N + 1;
  off = (off + 3) & ~(size_t)3;
  int* partials = ws_i + off; off += 128;
  int* ssrc    = ws_i + off; off += E;
  float* dinv  = (float*)(ws_i + off); off += N;
  off = (off + 3) & ~(size_t)3;
  float* hA    = (float*)(ws_i + off); off += (size_t)N * NFEAT;
  float* hB    = (float*)(ws_i + off); off += (size_t)N * NFEAT;

  hipMemsetAsync(deg, 0, (size_t)2 * N * sizeof(int), stream);  // deg + cursor

  const int tpbE = 256;
  const int gE = (E + tpbE - 1) / tpbE;
  k_deg<<<gE, tpbE, 0, stream>>>(dst, deg, E);

  const int nb = (N + 1023) / 1024;   // 98 for N=100000 (must be <= 128)
  k_scan_blocks<<<nb, 1024, 0, stream>>>(deg, base, partials, N);
  k_scan_partials<<<1, 128, 0, stream>>>(partials, nb);
  k_finalize_base<<<((N + 1) + 255) / 256, 256, 0, stream>>>(base, partials, deg, dinv, N, E);
  k_scatter<<<gE, tpbE, 0, stream>>>(src, dst, base, cursor, ssrc, E);

  const int gb = (N + 63) / 64;
  // layer 1: hA = (x @ W1) * dinv ; hB = relu(agg(hA) + b1)
  k_gemm_scale<<<gb, 512, 0, stream>>>(x, W1, dinv, hA, N);
  k_agg<<<N, 128, 0, stream>>>(hA, dinv, base, ssrc, b1, hB, 1);
  // layer 2: hA = (hB @ W2) * dinv ; hB = relu(agg(hA) + b2)
  k_gemm_scale<<<gb, 512, 0, stream>>>(hB, W2, dinv, hA, N);
  k_agg<<<N, 128, 0, stream>>>(hA, dinv, base, ssrc, b2, hB, 1);
  // final linear
  k_final<<<(N + 3) / 4, 256, 0, stream>>>(hB, Wlin, blin, (float*)d_out, N);
}

// Round 2
// 569.567 us; speedup vs baseline: 1.3798x; 1.3798x over previous
//
#include <hip/hip_runtime.h>

#define NFEAT 128

// ---------------- degree histogram + per-edge rank ----------------
__global__ void k_deg_rank(const int* __restrict__ dst, int* __restrict__ deg,
                           int* __restrict__ rank, int E) {
  int e = blockIdx.x * blockDim.x + threadIdx.x;
  if (e < E) rank[e] = atomicAdd(&deg[dst[e]], 1);
}

// ---------------- 2-level exclusive scan ----------------
__global__ __launch_bounds__(1024) void k_scan_blocks(const int* __restrict__ deg,
    int* __restrict__ base, int* __restrict__ partials, int n) {
  __shared__ int buf[1024];
  int tid = threadIdx.x;
  int i = blockIdx.x * 1024 + tid;
  int v = (i < n) ? deg[i] : 0;
  buf[tid] = v;
  __syncthreads();
  #pragma unroll
  for (int off = 1; off < 1024; off <<= 1) {
    int t = (tid >= off) ? buf[tid - off] : 0;
    __syncthreads();
    buf[tid] += t;
    __syncthreads();
  }
  if (i < n) base[i] = buf[tid] - v;   // exclusive prefix within block
  if (tid == 1023) partials[blockIdx.x] = buf[tid];
}

__global__ void k_scan_partials(int* __restrict__ partials, int nb) {
  __shared__ int buf[128];
  int tid = threadIdx.x;
  int v = (tid < nb) ? partials[tid] : 0;
  buf[tid] = v;
  __syncthreads();
  #pragma unroll
  for (int off = 1; off < 128; off <<= 1) {
    int t = (tid >= off) ? buf[tid - off] : 0;
    __syncthreads();
    buf[tid] += t;
    __syncthreads();
  }
  if (tid < nb) partials[tid] = buf[tid] - v;  // exclusive
}

__global__ void k_finalize_base(int* __restrict__ base, const int* __restrict__ partials,
    const int* __restrict__ deg, float* __restrict__ dinv, int n, int E) {
  int i = blockIdx.x * blockDim.x + threadIdx.x;
  if (i < n) {
    base[i] += partials[i >> 10];
    dinv[i] = rsqrtf((float)(deg[i] + 1));   // +1 self-loop
  } else if (i == n) {
    base[n] = E;
  }
}

// ---------------- bucket scatter using precomputed rank ----------------
__global__ void k_scatter(const int* __restrict__ src, const int* __restrict__ dst,
    const int* __restrict__ rank, const int* __restrict__ base,
    int* __restrict__ ssrc, int E) {
  int e = blockIdx.x * blockDim.x + threadIdx.x;
  if (e < E) ssrc[base[dst[e]] + rank[e]] = src[e];
}

// ---------------- LDS-tiled GEMM: C[r][:] = (A[r][:] @ B) * dinv[r] ----------------
// Block: 128 rows x 128 cols, 256 threads, 8x8 register tile per thread.
// A staged k-major (As[k][row]) so per-thread row fragments are b128 reads
// (broadcast across tx -> conflict-free). B column tile split (tx*4, tx*4+64)
// so Bs reads are 2-way bank aliased (free on gfx950).
__global__ __launch_bounds__(256) void k_gemm_scale(
    const float* __restrict__ A, const float* __restrict__ B,
    const float* __restrict__ dinv, float* __restrict__ C, int nrows) {
  __shared__ float As[32][132];
  __shared__ float Bs[32][132];
  const int tid = threadIdx.x;
  const int tx = tid & 15;   // 16 col groups
  const int ty = tid >> 4;   // 16 row groups
  const int row0 = blockIdx.x * 128;
  float acc[8][8] = {};

  for (int kt = 0; kt < 128; kt += 32) {
    #pragma unroll
    for (int i = 0; i < 4; i++) {
      int idx = tid + i * 256;       // 0..1023
      int r = idx >> 3;              // 0..127
      int kc = (idx & 7) * 4;        // 0..28
      int gr = row0 + r; gr = (gr < nrows) ? gr : (nrows - 1);
      float4 v = *(const float4*)(A + (size_t)gr * NFEAT + kt + kc);
      As[kc + 0][r] = v.x; As[kc + 1][r] = v.y;
      As[kc + 2][r] = v.z; As[kc + 3][r] = v.w;
    }
    #pragma unroll
    for (int i = 0; i < 4; i++) {
      int idx = tid + i * 256;
      int k = idx >> 5;              // 0..31
      int c = (idx & 31) * 4;        // 0..124
      *(float4*)&Bs[k][c] = *(const float4*)(B + (size_t)(kt + k) * NFEAT + c);
    }
    __syncthreads();
    #pragma unroll
    for (int k = 0; k < 32; k++) {
      float a[8], b[8];
      *(float4*)&a[0] = *(const float4*)&As[k][ty * 8];
      *(float4*)&a[4] = *(const float4*)&As[k][ty * 8 + 4];
      *(float4*)&b[0] = *(const float4*)&Bs[k][tx * 4];
      *(float4*)&b[4] = *(const float4*)&Bs[k][tx * 4 + 64];
      #pragma unroll
      for (int i = 0; i < 8; i++)
        #pragma unroll
        for (int j = 0; j < 8; j++)
          acc[i][j] += a[i] * b[j];
    }
    __syncthreads();
  }

  #pragma unroll
  for (int i = 0; i < 8; i++) {
    int r = row0 + ty * 8 + i;
    if (r < nrows) {
      float s = dinv[r];
      float4 o0 = make_float4(acc[i][0]*s, acc[i][1]*s, acc[i][2]*s, acc[i][3]*s);
      float4 o1 = make_float4(acc[i][4]*s, acc[i][5]*s, acc[i][6]*s, acc[i][7]*s);
      *(float4*)(C + (size_t)r * NFEAT + tx * 4) = o0;
      *(float4*)(C + (size_t)r * NFEAT + 64 + tx * 4) = o1;
    }
  }
}

// ---------------- per-node aggregation: out = relu(dinv[n]*(sum_src g + g[n]) + b)
__global__ __launch_bounds__(128) void k_agg(const float* __restrict__ g,
    const float* __restrict__ dinv, const int* __restrict__ base,
    const int* __restrict__ ssrc, const float* __restrict__ bias,
    float* __restrict__ out) {
  int n = blockIdx.x;
  int f = threadIdx.x;   // 0..127
  int b0 = base[n], b1 = base[n + 1];
  float acc = g[(size_t)n * NFEAT + f];   // self term (pre-scaled by dinv[n])
  int e = b0;
  for (; e + 8 <= b1; e += 8) {
    int s[8];
    #pragma unroll
    for (int i = 0; i < 8; i++) s[i] = ssrc[e + i];
    float v[8];
    #pragma unroll
    for (int i = 0; i < 8; i++) v[i] = g[(size_t)s[i] * NFEAT + f];
    #pragma unroll
    for (int i = 0; i < 8; i++) acc += v[i];
  }
  for (; e < b1; ++e) acc += g[(size_t)ssrc[e] * NFEAT + f];
  out[(size_t)n * NFEAT + f] = fmaxf(acc * dinv[n] + bias[f], 0.f);
}

// ---------------- layer-2 agg fused with final linear: out[n] = relu(h2[n]).Wlin + blin
__global__ __launch_bounds__(128) void k_agg_final(const float* __restrict__ g,
    const float* __restrict__ dinv, const int* __restrict__ base,
    const int* __restrict__ ssrc, const float* __restrict__ bias,
    const float* __restrict__ wlin, const float* __restrict__ blin,
    float* __restrict__ out) {
  __shared__ float red[2];
  int n = blockIdx.x;
  int f = threadIdx.x;
  int b0 = base[n], b1 = base[n + 1];
  float acc = g[(size_t)n * NFEAT + f];
  int e = b0;
  for (; e + 8 <= b1; e += 8) {
    int s[8];
    #pragma unroll
    for (int i = 0; i < 8; i++) s[i] = ssrc[e + i];
    float v[8];
    #pragma unroll
    for (int i = 0; i < 8; i++) v[i] = g[(size_t)s[i] * NFEAT + f];
    #pragma unroll
    for (int i = 0; i < 8; i++) acc += v[i];
  }
  for (; e < b1; ++e) acc += g[(size_t)ssrc[e] * NFEAT + f];
  float r = fmaxf(acc * dinv[n] + bias[f], 0.f);
  float p = r * wlin[f];
  #pragma unroll
  for (int off = 32; off >= 1; off >>= 1) p += __shfl_down(p, off, 64);
  if ((f & 63) == 0) red[f >> 6] = p;
  __syncthreads();
  if (f == 0) out[n] = red[0] + red[1] + blin[0];
}

extern "C" void kernel_launch(void* const* d_in, const int* in_sizes, int n_in,
                              void* d_out, int out_size, void* d_ws, size_t ws_size,
                              hipStream_t stream) {
  const float* x    = (const float*)d_in[0];
  const int*   ei   = (const int*)d_in[1];
  const float* W1   = (const float*)d_in[2];
  const float* b1   = (const float*)d_in[3];
  const float* W2   = (const float*)d_in[4];
  const float* b2   = (const float*)d_in[5];
  const float* Wlin = (const float*)d_in[6];
  const float* blin = (const float*)d_in[7];
  const int N = in_sizes[0] / NFEAT;
  const int E = in_sizes[1] / 2;
  const int* src = ei;       // edge_index[0]
  const int* dst = ei + E;   // edge_index[1]

  // workspace layout (4B elements)
  int* ws_i = (int*)d_ws;
  size_t off = 0;
  int* deg      = ws_i + off; off += N;
  int* base     = ws_i + off; off += (size_t)N + 1;
  off = (off + 3) & ~(size_t)3;
  int* partials = ws_i + off; off += 128;
  int* ssrc     = ws_i + off; off += E;
  float* dinv   = (float*)(ws_i + off); off += N;
  off = (off + 3) & ~(size_t)3;
  float* hA     = (float*)(ws_i + off); off += (size_t)N * NFEAT;
  float* hB     = (float*)(ws_i + off); off += (size_t)N * NFEAT;
  // rank[E] aliases hA: consumed by k_scatter before GEMM1 writes hA
  int* rank     = (int*)hA;

  hipMemsetAsync(deg, 0, (size_t)N * sizeof(int), stream);

  const int tpbE = 256;
  const int gE = (E + tpbE - 1) / tpbE;
  k_deg_rank<<<gE, tpbE, 0, stream>>>(dst, deg, rank, E);

  const int nb = (N + 1023) / 1024;   // 98 blocks for N=100000 (<=128)
  k_scan_blocks<<<nb, 1024, 0, stream>>>(deg, base, partials, N);
  k_scan_partials<<<1, 128, 0, stream>>>(partials, nb);
  k_finalize_base<<<((N + 1) + 255) / 256, 256, 0, stream>>>(base, partials, deg, dinv, N, E);
  k_scatter<<<gE, tpbE, 0, stream>>>(src, dst, rank, base, ssrc, E);

  const int gb = (N + 127) / 128;
  // layer 1: hA = (x @ W1) * dinv ; hB = relu(agg(hA) + b1)
  k_gemm_scale<<<gb, 256, 0, stream>>>(x, W1, dinv, hA, N);
  k_agg<<<N, 128, 0, stream>>>(hA, dinv, base, ssrc, b1, hB);
  // layer 2: hA = (hB @ W2) * dinv ; fused agg + relu + final linear
  k_gemm_scale<<<gb, 256, 0, stream>>>(hB, W2, dinv, hA, N);
  k_agg_final<<<N, 128, 0, stream>>>(hA, dinv, base, ssrc, b2, Wlin, blin, (float*)d_out);
}

// Round 3
// 480.528 us; speedup vs baseline: 1.6355x; 1.1853x over previous
//
#include <hip/hip_runtime.h>
#include <hip/hip_fp16.h>

#define NFEAT 128

// ---------------- degree histogram + per-edge rank ----------------
__global__ void k_deg_rank(const int* __restrict__ dst, int* __restrict__ deg,
                           int* __restrict__ rank, int E) {
  int e = blockIdx.x * blockDim.x + threadIdx.x;
  if (e < E) rank[e] = atomicAdd(&deg[dst[e]], 1);
}

// ---------------- 2-level exclusive scan ----------------
__global__ __launch_bounds__(1024) void k_scan_blocks(const int* __restrict__ deg,
    int* __restrict__ base, int* __restrict__ partials, int n) {
  __shared__ int buf[1024];
  int tid = threadIdx.x;
  int i = blockIdx.x * 1024 + tid;
  int v = (i < n) ? deg[i] : 0;
  buf[tid] = v;
  __syncthreads();
  #pragma unroll
  for (int off = 1; off < 1024; off <<= 1) {
    int t = (tid >= off) ? buf[tid - off] : 0;
    __syncthreads();
    buf[tid] += t;
    __syncthreads();
  }
  if (i < n) base[i] = buf[tid] - v;   // exclusive prefix within block
  if (tid == 1023) partials[blockIdx.x] = buf[tid];
}

__global__ void k_scan_partials(int* __restrict__ partials, int nb) {
  __shared__ int buf[128];
  int tid = threadIdx.x;
  int v = (tid < nb) ? partials[tid] : 0;
  buf[tid] = v;
  __syncthreads();
  #pragma unroll
  for (int off = 1; off < 128; off <<= 1) {
    int t = (tid >= off) ? buf[tid - off] : 0;
    __syncthreads();
    buf[tid] += t;
    __syncthreads();
  }
  if (tid < nb) partials[tid] = buf[tid] - v;  // exclusive
}

__global__ void k_finalize_base(int* __restrict__ base, const int* __restrict__ partials,
    const int* __restrict__ deg, float* __restrict__ dinv, int n, int E) {
  int i = blockIdx.x * blockDim.x + threadIdx.x;
  if (i < n) {
    base[i] += partials[i >> 10];
    dinv[i] = rsqrtf((float)(deg[i] + 1));   // +1 self-loop
  } else if (i == n) {
    base[n] = E;
  }
}

// ---------------- bucket scatter using precomputed rank ----------------
__global__ void k_scatter(const int* __restrict__ src, const int* __restrict__ dst,
    const int* __restrict__ rank, const int* __restrict__ base,
    int* __restrict__ ssrc, int E) {
  int e = blockIdx.x * blockDim.x + threadIdx.x;
  if (e < E) ssrc[base[dst[e]] + rank[e]] = src[e];
}

// ---------------- LDS-tiled GEMM: C16[r][:] = half((A[r][:] @ B) * dinv[r]) ----
// 128x128 block, 256 threads, 8x8 register tile. Software-pipelined k-tiles:
// next tile's global loads issued before compute so VMEM overlaps FMA.
__global__ __launch_bounds__(256) void k_gemm_scale(
    const float* __restrict__ A, const float* __restrict__ B,
    const float* __restrict__ dinv, __half* __restrict__ C, int nrows) {
  __shared__ float As[32][132];
  __shared__ float Bs[32][132];
  const int tid = threadIdx.x;
  const int tx = tid & 15;   // 16 col groups
  const int ty = tid >> 4;   // 16 row groups
  const int row0 = blockIdx.x * 128;

  int ar[4], ak[4], bk[4], bc[4];
  const float* aptr[4];
  const float* bptr[4];
  #pragma unroll
  for (int i = 0; i < 4; i++) {
    int idx = tid + i * 256;          // 0..1023
    ar[i] = idx >> 3;                 // 0..127
    ak[i] = (idx & 7) * 4;            // 0..28
    int gr = row0 + ar[i]; gr = (gr < nrows) ? gr : (nrows - 1);
    aptr[i] = A + (size_t)gr * NFEAT + ak[i];
    bk[i] = idx >> 5;                 // 0..31
    bc[i] = (idx & 31) * 4;           // 0..124
    bptr[i] = B + (size_t)bk[i] * NFEAT + bc[i];
  }
  float4 ra[4], rb[4];
  #pragma unroll
  for (int i = 0; i < 4; i++) {
    ra[i] = *(const float4*)(aptr[i]);
    rb[i] = *(const float4*)(bptr[i]);
  }

  float acc[8][8] = {};
  for (int kt = 0; kt < 128; kt += 32) {
    #pragma unroll
    for (int i = 0; i < 4; i++) {
      As[ak[i] + 0][ar[i]] = ra[i].x; As[ak[i] + 1][ar[i]] = ra[i].y;
      As[ak[i] + 2][ar[i]] = ra[i].z; As[ak[i] + 3][ar[i]] = ra[i].w;
      *(float4*)&Bs[bk[i]][bc[i]] = rb[i];
    }
    __syncthreads();
    if (kt + 32 < 128) {
      #pragma unroll
      for (int i = 0; i < 4; i++) {
        ra[i] = *(const float4*)(aptr[i] + kt + 32);
        rb[i] = *(const float4*)(bptr[i] + (size_t)(kt + 32) * NFEAT);
      }
    }
    #pragma unroll
    for (int k = 0; k < 32; k++) {
      float a[8], b[8];
      *(float4*)&a[0] = *(const float4*)&As[k][ty * 8];
      *(float4*)&a[4] = *(const float4*)&As[k][ty * 8 + 4];
      *(float4*)&b[0] = *(const float4*)&Bs[k][tx * 4];
      *(float4*)&b[4] = *(const float4*)&Bs[k][tx * 4 + 64];
      #pragma unroll
      for (int i = 0; i < 8; i++)
        #pragma unroll
        for (int j = 0; j < 8; j++)
          acc[i][j] += a[i] * b[j];
    }
    __syncthreads();
  }

  #pragma unroll
  for (int i = 0; i < 8; i++) {
    int r = row0 + ty * 8 + i;
    if (r < nrows) {
      float s = dinv[r];
      union { __half2 h[2]; uint2 u; } p0, p1;
      p0.h[0] = __floats2half2_rn(acc[i][0] * s, acc[i][1] * s);
      p0.h[1] = __floats2half2_rn(acc[i][2] * s, acc[i][3] * s);
      p1.h[0] = __floats2half2_rn(acc[i][4] * s, acc[i][5] * s);
      p1.h[1] = __floats2half2_rn(acc[i][6] * s, acc[i][7] * s);
      *(uint2*)(C + (size_t)r * NFEAT + tx * 4) = p0.u;
      *(uint2*)(C + (size_t)r * NFEAT + 64 + tx * 4) = p1.u;
    }
  }
}

// ---------------- agg (fp16 gather, wave-per-node): out = relu(dinv*(sum g)+b)
__global__ __launch_bounds__(256) void k_agg(const __half2* __restrict__ g,
    const float* __restrict__ dinv, const int* __restrict__ base,
    const int* __restrict__ ssrc, const float* __restrict__ bias,
    float* __restrict__ out, int N) {
  int lane = threadIdx.x & 63;
  int n = blockIdx.x * 4 + (threadIdx.x >> 6);
  if (n >= N) return;
  int b0 = base[n], b1 = base[n + 1];
  float2 acc = __half22float2(g[(size_t)n * 64 + lane]);   // self term
  int e = b0;
  for (; e + 8 <= b1; e += 8) {
    int s[8];
    #pragma unroll
    for (int i = 0; i < 8; i++) s[i] = ssrc[e + i];
    __half2 v[8];
    #pragma unroll
    for (int i = 0; i < 8; i++) v[i] = g[(size_t)s[i] * 64 + lane];
    #pragma unroll
    for (int i = 0; i < 8; i++) {
      float2 f = __half22float2(v[i]);
      acc.x += f.x; acc.y += f.y;
    }
  }
  for (; e < b1; ++e) {
    float2 f = __half22float2(g[(size_t)ssrc[e] * 64 + lane]);
    acc.x += f.x; acc.y += f.y;
  }
  float s = dinv[n];
  float2 bb = *(const float2*)(bias + lane * 2);
  float2 r = make_float2(fmaxf(acc.x * s + bb.x, 0.f), fmaxf(acc.y * s + bb.y, 0.f));
  *(float2*)(out + (size_t)n * NFEAT + lane * 2) = r;
}

// ---------------- layer-2 agg fused with final linear (wave-per-node) --------
__global__ __launch_bounds__(256) void k_agg_final(const __half2* __restrict__ g,
    const float* __restrict__ dinv, const int* __restrict__ base,
    const int* __restrict__ ssrc, const float* __restrict__ bias,
    const float* __restrict__ wlin, const float* __restrict__ blin,
    float* __restrict__ out, int N) {
  int lane = threadIdx.x & 63;
  int n = blockIdx.x * 4 + (threadIdx.x >> 6);
  if (n >= N) return;
  int b0 = base[n], b1 = base[n + 1];
  float2 acc = __half22float2(g[(size_t)n * 64 + lane]);
  int e = b0;
  for (; e + 8 <= b1; e += 8) {
    int s[8];
    #pragma unroll
    for (int i = 0; i < 8; i++) s[i] = ssrc[e + i];
    __half2 v[8];
    #pragma unroll
    for (int i = 0; i < 8; i++) v[i] = g[(size_t)s[i] * 64 + lane];
    #pragma unroll
    for (int i = 0; i < 8; i++) {
      float2 f = __half22float2(v[i]);
      acc.x += f.x; acc.y += f.y;
    }
  }
  for (; e < b1; ++e) {
    float2 f = __half22float2(g[(size_t)ssrc[e] * 64 + lane]);
    acc.x += f.x; acc.y += f.y;
  }
  float s = dinv[n];
  float2 bb = *(const float2*)(bias + lane * 2);
  float2 wl = *(const float2*)(wlin + lane * 2);
  float p = fmaxf(acc.x * s + bb.x, 0.f) * wl.x + fmaxf(acc.y * s + bb.y, 0.f) * wl.y;
  #pragma unroll
  for (int off = 32; off >= 1; off >>= 1) p += __shfl_down(p, off, 64);
  if (lane == 0) out[n] = p + blin[0];
}

extern "C" void kernel_launch(void* const* d_in, const int* in_sizes, int n_in,
                              void* d_out, int out_size, void* d_ws, size_t ws_size,
                              hipStream_t stream) {
  const float* x    = (const float*)d_in[0];
  const int*   ei   = (const int*)d_in[1];
  const float* W1   = (const float*)d_in[2];
  const float* b1   = (const float*)d_in[3];
  const float* W2   = (const float*)d_in[4];
  const float* b2   = (const float*)d_in[5];
  const float* Wlin = (const float*)d_in[6];
  const float* blin = (const float*)d_in[7];
  const int N = in_sizes[0] / NFEAT;
  const int E = in_sizes[1] / 2;
  const int* src = ei;       // edge_index[0]
  const int* dst = ei + E;   // edge_index[1]

  // workspace layout (4B elements)
  int* ws_i = (int*)d_ws;
  size_t off = 0;
  int* deg      = ws_i + off; off += N;
  int* base     = ws_i + off; off += (size_t)N + 1;
  off = (off + 3) & ~(size_t)3;
  int* partials = ws_i + off; off += 128;
  int* ssrc     = ws_i + off; off += E;
  float* dinv   = (float*)(ws_i + off); off += N;
  off = (off + 3) & ~(size_t)3;
  __half* hA    = (__half*)(ws_i + off); off += (size_t)N * 64;   // fp16 gather table
  float* hB     = (float*)(ws_i + off); off += (size_t)N * NFEAT;
  // rank[E] aliases hA: consumed by k_scatter before GEMM1 writes hA (E*4B < N*128*2B)
  int* rank     = (int*)hA;

  hipMemsetAsync(deg, 0, (size_t)N * sizeof(int), stream);

  const int tpbE = 256;
  const int gE = (E + tpbE - 1) / tpbE;
  k_deg_rank<<<gE, tpbE, 0, stream>>>(dst, deg, rank, E);

  const int nb = (N + 1023) / 1024;   // 98 blocks for N=100000 (<=128)
  k_scan_blocks<<<nb, 1024, 0, stream>>>(deg, base, partials, N);
  k_scan_partials<<<1, 128, 0, stream>>>(partials, nb);
  k_finalize_base<<<((N + 1) + 255) / 256, 256, 0, stream>>>(base, partials, deg, dinv, N, E);
  k_scatter<<<gE, tpbE, 0, stream>>>(src, dst, rank, base, ssrc, E);

  const int gb = (N + 127) / 128;
  const int ga = (N + 3) / 4;
  // layer 1: hA = half((x @ W1) * dinv) ; hB = relu(agg(hA) + b1)
  k_gemm_scale<<<gb, 256, 0, stream>>>(x, W1, dinv, hA, N);
  k_agg<<<ga, 256, 0, stream>>>((const __half2*)hA, dinv, base, ssrc, b1, hB, N);
  // layer 2: hA = half((hB @ W2) * dinv) ; fused agg + relu + final linear
  k_gemm_scale<<<gb, 256, 0, stream>>>(hB, W2, dinv, hA, N);
  k_agg_final<<<ga, 256, 0, stream>>>((const __half2*)hA, dinv, base, ssrc, b2,
                                      Wlin, blin, (float*)d_out, N);
}